// Round 1
// baseline (377.982 us; speedup 1.0000x reference)
//
#include <hip/hip_runtime.h>
#include <stdint.h>

typedef unsigned short u16;
typedef short short8 __attribute__((ext_vector_type(8)));
typedef float f32x4 __attribute__((ext_vector_type(4)));

// Problem sizes: B=16384, D=768, E=124 (pad 128), C=6, E*C=744 (pad 768)

// ---- workspace layout (bytes) ---- (unchanged from prior passing version)
#define OFF_XHI      0ull            // bf16 [16384][768]
#define OFF_XLO      25165824ull     // bf16 [16384][768]
#define OFF_LCLS     0ull            // aliases XHI: bf16 [16384][768] class logits
#define OFF_LWE_P0   25165824ull     // f32 [16384][128] we partial (hi+lo)*Whi + bias (aliases XLO)
#define OFF_LWE_P1   33554432ull     // f32 [16384][128] we partial (hi+lo)*Wlo
#define OFF_BT1      50331648ull     // bf16 [1536][768]  (cls_w1^T ; ew_w1^T)  [dead after gemm1]
#define OFF_LEWB     50331648ull     // bf16 [16384][128] ew logits (aliases BT1+, written in gemm2)
#define OFF_BTWE_HI  52690944ull     // bf16 [768][768]
#define OFF_BTWE_LO  53870592ull
#define OFF_BT2CLS   55050240ull     // bf16 [768][768] (744 real rows, zero pad)
#define OFF_BT2EW    56229888ull     // bf16 [128][768]
#define OFF_BT2WE_HI 56426496ull     // bf16 [128][768]  } adjacent => stacked [256][768]
#define OFF_BT2WE_LO 56623104ull     // bf16 [128][768]  }
#define OFF_B1CE     56819712ull     // f32 [1536]
#define OFF_B1WE     56825856ull     // f32 [768]
#define OFF_B2CLS    56828928ull     // f32 [768]
#define OFF_B2EW     56832000ull     // f32 [128]
#define OFF_B2WE     56832512ull     // f32 [128]
#define OFF_HCLSEW   56833024ull     // bf16 [16384][1536] gelu(h) for cls|ew
#define OFF_HWE_HI   107164672ull    // bf16 [16384][768]
#define OFF_HWE_LO   132330496ull    // bf16 [16384][768]
#define WS_NEED      157496320ull

__device__ __forceinline__ u16 f2bf(float f) {          // RNE f32->bf16
  uint32_t u = __float_as_uint(f);
  u += 0x7fffu + ((u >> 16) & 1u);
  return (u16)(u >> 16);
}
__device__ __forceinline__ float bf2f(u16 h) {
  return __uint_as_float(((uint32_t)h) << 16);
}
__device__ __forceinline__ void g2l16(const u16* g, u16* l) {
  // async global->LDS, 16B/lane; LDS dest = wave-uniform base + lane*16 (HW rule).
  // Global source is per-lane -> swizzle achieved by pre-permuting the source address.
  __builtin_amdgcn_global_load_lds(
      (__attribute__((address_space(1))) void*)(u16*)g,
      (__attribute__((address_space(3))) void*)l, 16, 0, 0);
}

// branch-free exact-GELU: 0.5*v*(1+erf(v/sqrt2)), erf via A&S 7.1.26 (|eps|<=1.5e-7).
// Replaces libm erff: with 1 block/CU the epilogue VALU is exposed, so it must be lean.
__device__ __forceinline__ float gelu_exact(float v) {
  const float x = fabsf(v) * 0.70710678118654752f;
  const float t = __fdividef(1.0f, __builtin_fmaf(0.3275911f, x, 1.0f));
  float p = __builtin_fmaf(1.061405429f, t, -1.453152027f);
  p = __builtin_fmaf(p, t, 1.421413741f);
  p = __builtin_fmaf(p, t, -0.284496736f);
  p = __builtin_fmaf(p, t, 0.254829592f);
  p = p * t;
  const float e = __expf(-x * x);
  float erfx = __builtin_fmaf(-p, e, 1.0f);
  erfx = (v < 0.f) ? -erfx : erfx;
  return 0.5f * v * (1.0f + erfx);
}

// ---------------- merged prep: cvt_x split + weight transposes + bias concat ----------------
// grid layout: [0,12288) cvt_x ; [12288,13152) transpose (12x12x6) ; [13152,13165) bias
__global__ void prep_all(
    const float* __restrict__ x, u16* __restrict__ xhi, u16* __restrict__ xlo,
    const float* __restrict__ cls_w1, const float* __restrict__ ew_w1,
    const float* __restrict__ we_w1,  const float* __restrict__ cls_w2,
    const float* __restrict__ ew_w2,  const float* __restrict__ we_w2,
    u16* BT1, u16* BTwe_hi, u16* BTwe_lo,
    u16* BT2cls, u16* BT2ew, u16* BT2we_hi, u16* BT2we_lo,
    const float* __restrict__ cls_b1, const float* __restrict__ ew_b1,
    const float* __restrict__ we_b1,  const float* __restrict__ cls_b2,
    const float* __restrict__ ew_b2,  const float* __restrict__ we_b2,
    float* b1ce, float* b1we, float* b2cls, float* b2ew, float* b2we) {
  __shared__ float t[64][65];
  const int bid = blockIdx.x;
  if (bid < 12288) {                       // ---- x -> (hi,lo) bf16 split
    int i = bid * 256 + threadIdx.x;       // 12288*256 = 16384*768/4 exact
    float4 v = ((const float4*)x)[i];
    ushort4 h, l;
    h.x = f2bf(v.x); l.x = f2bf(v.x - bf2f(h.x));
    h.y = f2bf(v.y); l.y = f2bf(v.y - bf2f(h.y));
    h.z = f2bf(v.z); l.z = f2bf(v.z - bf2f(h.z));
    h.w = f2bf(v.w); l.w = f2bf(v.w - bf2f(h.w));
    ((ushort4*)xhi)[i] = h;
    ((ushort4*)xlo)[i] = l;
    return;
  }
  if (bid < 13152) {                       // ---- LDS-tiled transpose W[768][N] -> BT[Npad][768]
    const int idx = bid - 12288;
    const int bx = idx % 12, by = (idx / 12) % 12, bz = idx / 144;
    const float* src; int N; u16* dhi; u16* dlo = nullptr;
    switch (bz) {
      case 0: src = cls_w1; N = 768; dhi = BT1; break;
      case 1: src = ew_w1;  N = 768; dhi = BT1 + 768 * 768; break;
      case 2: src = we_w1;  N = 768; dhi = BTwe_hi; dlo = BTwe_lo; break;
      case 3: src = cls_w2; N = 744; dhi = BT2cls; break;
      case 4: src = ew_w2;  N = 124; dhi = BT2ew; break;
      default: src = we_w2; N = 124; dhi = BT2we_hi; dlo = BT2we_lo; break;
    }
    const int Npad = (N + 127) & ~127;
    const int n0 = by * 64;
    if (n0 >= Npad) return;
    const int k0 = bx * 64;
    const int tx = threadIdx.x & 63, tg = threadIdx.x >> 6;
#pragma unroll
    for (int r = 0; r < 16; ++r) {
      int k = tg * 16 + r;
      int n = n0 + tx;
      t[k][tx] = (n < N) ? src[(size_t)(k0 + k) * N + n] : 0.f;   // coalesced read
    }
    __syncthreads();
#pragma unroll
    for (int r = 0; r < 16; ++r) {
      int n = n0 + tg * 16 + r;
      if (n < Npad) {
        float v = t[tx][tg * 16 + r];
        u16 h = f2bf(v);
        dhi[(size_t)n * 768 + k0 + tx] = h;                       // coalesced write
        if (dlo) dlo[(size_t)n * 768 + k0 + tx] = f2bf(v - bf2f(h));
      }
    }
    return;
  }
  // ---- bias concat/pad: 13 blocks * 256 = 3328 = 1536+768+768+128+128 exact
  int id = (bid - 13152) * 256 + threadIdx.x;
  if (id < 1536) { b1ce[id] = (id < 768) ? cls_b1[id] : ew_b1[id - 768]; return; }
  id -= 1536;
  if (id < 768) { b1we[id] = we_b1[id]; return; }
  id -= 768;
  if (id < 768) { b2cls[id] = (id < 744) ? cls_b2[id] : 0.f; return; }
  id -= 768;
  if (id < 128) { b2ew[id] = (id < 124) ? ew_b2[id] : 0.f; return; }
  id -= 128;
  if (id < 128) { b2we[id] = (id < 124) ? we_b2[id] : 0.f; return; }
}

// ======================= 256x256 8-phase GEMM core =======================
// 512 threads = 8 waves (2M x 4N), per-wave C = 128x64 = acc[8][4] f32x4.
// LDS 128 KiB: 2 buffers x (A 256x64 + B 256x64) bf16, XOR-granule swizzle
// (phys granule = logical ^ (row&7), proven conflict-free; linear global_load_lds
// dest + pre-swizzled per-lane global source).
// Schedule: 4 phases per K-tile, 8 per double-tile iteration. Counted vmcnt(6)
// only at phases 4/8 (2 K-tiles staged ahead, 3 half-tiles in flight); never
// vmcnt(0) in steady state. setprio(1) around each 16-MFMA cluster.
// Stage half-tiles are matched to regions freed by the previous phase's reads:
//   A half h: rows {h*64..h*64+63} u {128+h*64..128+h*64+63} (quarters)
//   B half h: rows {h*128..h*128+127}
// Multi-pass: K-loop walks NPASS (A,B) pointer pairs (precision-split fusion).
// Requires: NT = NPASS*ktpp even and >= 2.

__device__ __forceinline__ void stage_half(const u16* gsrc, int ld, u16* smem,
                                           int bufsel, int isB, int h,
                                           int wv, int srow, int scol) {
  const int rb = isB ? (h << 7) : (h << 6);
  const int rs = isB ? 64 : 128;
  u16* lb = smem + bufsel * 32768 + isB * 16384 + (rb + (wv << 3)) * 64;
  const u16* gs = gsrc + (size_t)(rb + (wv << 3) + srow) * ld + scol;
  g2l16(gs, lb);
  g2l16(gs + (size_t)rs * ld, lb + rs * 64);
}

__device__ __forceinline__ void rd_a(const u16* base, int wr, int lane, int mh,
                                     short8 a[4][2]) {
  const int r0 = wr * 128 + mh * 64 + (lane & 15);
  const int g0 = lane >> 4;
#pragma unroll
  for (int i = 0; i < 4; ++i)
#pragma unroll
    for (int ks = 0; ks < 2; ++ks) {
      const int pg = (ks * 4 + g0) ^ (lane & 7);
      a[i][ks] = *(const short8*)(base + (size_t)(r0 + i * 16) * 64 + pg * 8);
    }
}
__device__ __forceinline__ void rd_b(const u16* base, int wc, int lane, int nh,
                                     short8 b[2][2]) {
  const int r0 = wc * 64 + nh * 32 + (lane & 15);
  const int g0 = lane >> 4;
#pragma unroll
  for (int j = 0; j < 2; ++j)
#pragma unroll
    for (int ks = 0; ks < 2; ++ks) {
      const int pg = (ks * 4 + g0) ^ (lane & 7);
      b[j][ks] = *(const short8*)(base + (size_t)(r0 + j * 16) * 64 + pg * 8);
    }
}

#define PH_WAIT()                                          \
  __builtin_amdgcn_s_barrier();                            \
  asm volatile("s_waitcnt lgkmcnt(0)" ::: "memory");       \
  __builtin_amdgcn_sched_barrier(0);

template <int NPASS>
__device__ __forceinline__ void gemm256_core(
    const u16* A0, const u16* A1, const u16* A2, int lda,
    const u16* B0, const u16* B1, const u16* B2, int ldb,
    int ktpp, int tid, u16* smem, f32x4 acc[8][4]) {
  const int lane = tid & 63;
  const int wv = tid >> 6;
  const int wr = wv >> 2, wc = wv & 3;
  const int srow = lane >> 3;
  const int scol = ((lane & 7) ^ srow) << 3;
  const int NT = NPASS * ktpp;

  auto aP = [&](int nt) -> const u16* {
    int p = 0, kk = nt;
    if (NPASS > 1 && kk >= ktpp) { kk -= ktpp; ++p; }
    if (NPASS > 2 && kk >= ktpp) { kk -= ktpp; ++p; }
    const u16* base = (p == 0) ? A0 : ((p == 1) ? A1 : A2);
    return base + kk * 64;
  };
  auto bP = [&](int nt) -> const u16* {
    int p = 0, kk = nt;
    if (NPASS > 1 && kk >= ktpp) { kk -= ktpp; ++p; }
    if (NPASS > 2 && kk >= ktpp) { kk -= ktpp; ++p; }
    const u16* base = (p == 0) ? B0 : ((p == 1) ? B1 : B2);
    return base + kk * 64;
  };
  auto mmaQ = [&](int mh, int nh, short8 (&av)[4][2], short8 (&bv)[2][2]) {
    __builtin_amdgcn_s_setprio(1);
#pragma unroll
    for (int i = 0; i < 4; ++i)
#pragma unroll
      for (int j = 0; j < 2; ++j)
#pragma unroll
        for (int ks = 0; ks < 2; ++ks)
          acc[mh * 4 + i][nh * 2 + j] = __builtin_amdgcn_mfma_f32_16x16x32_bf16(
              av[i][ks], bv[j][ks], acc[mh * 4 + i][nh * 2 + j], 0, 0, 0);
    __builtin_amdgcn_s_setprio(0);
  };

  // ---- prologue: stage tiles 0,1 in steady-state issue order (7 halves)
  {
    const u16* a0p = aP(0); const u16* b0p = bP(0);
    const u16* a1p = aP(1); const u16* b1p = bP(1);
    stage_half(a0p, lda, smem, 0, 0, 0, wv, srow, scol);  // 0.A0'
    stage_half(b0p, ldb, smem, 0, 1, 1, wv, srow, scol);  // 0.B1'
    stage_half(a0p, lda, smem, 0, 0, 1, wv, srow, scol);  // 0.A1'
    stage_half(b0p, ldb, smem, 0, 1, 0, wv, srow, scol);  // 0.B0'
    stage_half(a1p, lda, smem, 1, 0, 0, wv, srow, scol);  // 1.A0'
    stage_half(b1p, ldb, smem, 1, 1, 1, wv, srow, scol);  // 1.B1'
    stage_half(a1p, lda, smem, 1, 0, 1, wv, srow, scol);  // 1.A1'
  }
  asm volatile("s_waitcnt vmcnt(6)" ::: "memory");   // tile0 fully landed
  __builtin_amdgcn_s_barrier();

  const u16* sA0 = smem;
  const u16* sB0 = smem + 16384;
  const u16* sA1 = smem + 32768;
  const u16* sB1 = smem + 32768 + 16384;

  short8 a[4][2], b0v[2][2], b1v[2][2];

  for (int t = 0; t < NT; t += 2) {
    const bool more = (t + 2 < NT);
    const u16* a2p = more ? aP(t + 2) : A0;
    const u16* b2p = more ? bP(t + 2) : B0;
    const u16* a3p = more ? aP(t + 3) : A0;
    const u16* b3p = more ? bP(t + 3) : B0;
    const u16* b1p_ = bP(t + 1);

    // ---- P1: tile t, quadrant (0,0)
    stage_half(b1p_, ldb, smem, 1, 1, 0, wv, srow, scol);          // (t+1).B0'
    rd_a(sA0, wr, lane, 0, a);
    rd_b(sB0, wc, lane, 0, b0v);
    PH_WAIT();
    mmaQ(0, 0, a, b0v);
    __builtin_amdgcn_s_barrier();
    // ---- P2: quadrant (0,1)
    if (more) stage_half(a2p, lda, smem, 0, 0, 0, wv, srow, scol); // (t+2).A0'
    rd_b(sB0, wc, lane, 1, b1v);
    PH_WAIT();
    mmaQ(0, 1, a, b1v);
    __builtin_amdgcn_s_barrier();
    // ---- P3: quadrant (1,1)
    if (more) stage_half(b2p, ldb, smem, 0, 1, 1, wv, srow, scol); // (t+2).B1'
    rd_a(sA0, wr, lane, 1, a);
    PH_WAIT();
    mmaQ(1, 1, a, b1v);
    __builtin_amdgcn_s_barrier();
    // ---- P4: quadrant (1,0), B0 frags held in regs; per-K-tile vmcnt
    if (more) stage_half(a2p, lda, smem, 0, 0, 1, wv, srow, scol); // (t+2).A1'
    __builtin_amdgcn_s_barrier();
    mmaQ(1, 0, a, b0v);
    if (more) asm volatile("s_waitcnt vmcnt(6)" ::: "memory");
    else      asm volatile("s_waitcnt vmcnt(0)" ::: "memory");
    __builtin_amdgcn_s_barrier();
    // ---- P5: tile t+1 (buf1), quadrant (0,0)
    if (more) stage_half(b2p, ldb, smem, 0, 1, 0, wv, srow, scol); // (t+2).B0'
    rd_a(sA1, wr, lane, 0, a);
    rd_b(sB1, wc, lane, 0, b0v);
    PH_WAIT();
    mmaQ(0, 0, a, b0v);
    __builtin_amdgcn_s_barrier();
    // ---- P6
    if (more) stage_half(a3p, lda, smem, 1, 0, 0, wv, srow, scol); // (t+3).A0'
    rd_b(sB1, wc, lane, 1, b1v);
    PH_WAIT();
    mmaQ(0, 1, a, b1v);
    __builtin_amdgcn_s_barrier();
    // ---- P7
    if (more) stage_half(b3p, ldb, smem, 1, 1, 1, wv, srow, scol); // (t+3).B1'
    rd_a(sA1, wr, lane, 1, a);
    PH_WAIT();
    mmaQ(1, 1, a, b1v);
    __builtin_amdgcn_s_barrier();
    // ---- P8
    if (more) stage_half(a3p, lda, smem, 1, 0, 1, wv, srow, scol); // (t+3).A1'
    __builtin_amdgcn_s_barrier();
    mmaQ(1, 0, a, b0v);
    if (more) asm volatile("s_waitcnt vmcnt(6)" ::: "memory");
    __builtin_amdgcn_s_barrier();
  }
}

// XCD/L2 swizzle for 256-row tiles: xcd = bid&7 owns 8 consecutive m-tiles, rows fastest.
__device__ __forceinline__ void decode256(int bid, int& bm, int& bn) {
  const int xcd = bid & 7, slot = bid >> 3;
  bm = ((xcd << 3) + (slot & 7)) << 8;
  bn = (slot >> 3) << 8;
}

// ---------------- fused fc1: BOTH heads, 576 blocks of 256x256 ----------------
//   bid [0,192)   -> which_expert packed-split (npass=3, heavy ~3x -> first)
//   bid [192,576) -> cls+ew (N=1536)
__global__ __launch_bounds__(512, 2) void gemm1_fused(
    const u16* __restrict__ Ahi, const u16* __restrict__ Alo,
    const u16* __restrict__ Bwe_hi, const u16* __restrict__ Bwe_lo,
    const u16* __restrict__ BT1,
    const float* __restrict__ b1we, const float* __restrict__ b1ce,
    u16* __restrict__ out_we_hi, u16* __restrict__ out_we_lo,
    u16* __restrict__ out_ce) {
  __shared__ u16 smem[65536];
  const int tid = threadIdx.x;
  const int lane = tid & 63;
  const int wv = tid >> 6;
  const int wr = wv >> 2, wc = wv & 3;
  f32x4 acc[8][4];
#pragma unroll
  for (int i = 0; i < 8; i++)
#pragma unroll
    for (int j = 0; j < 4; j++) acc[i][j] = f32x4{0.f, 0.f, 0.f, 0.f};

  if (blockIdx.x < 192) {
    // ===== which_expert fc1: hi*Whi + lo*Whi + hi*Wlo fused in one acc =====
    int bm, bn;
    decode256(blockIdx.x, bm, bn);
    gemm256_core<3>(Ahi + (size_t)bm * 768, Alo + (size_t)bm * 768,
                    Ahi + (size_t)bm * 768, 768,
                    Bwe_hi + (size_t)bn * 768, Bwe_hi + (size_t)bn * 768,
                    Bwe_lo + (size_t)bn * 768, 768,
                    12, tid, smem, acc);
#pragma unroll
    for (int j = 0; j < 4; j++) {
      const int col = bn + wc * 64 + ((j >> 1) << 5) + ((j & 1) << 4) + (lane & 15);
      const float bs = b1we[col];
#pragma unroll
      for (int i = 0; i < 8; i++) {
        const int row0 = bm + wr * 128 + ((i >> 2) << 6) + ((i & 3) << 4) + ((lane >> 4) << 2);
#pragma unroll
        for (int r = 0; r < 4; r++) {
          float g = gelu_exact(acc[i][j][r] + bs);
          const size_t idx = (size_t)(row0 + r) * 768 + col;
          u16 h = f2bf(g);
          out_we_hi[idx] = h;
          out_we_lo[idx] = f2bf(g - bf2f(h));
        }
      }
    }
  } else {
    // ===== cls+ew fc1 (N=1536) =====
    int bm, bn;
    decode256(blockIdx.x - 192, bm, bn);
    gemm256_core<1>(Ahi + (size_t)bm * 768, nullptr, nullptr, 768,
                    BT1 + (size_t)bn * 768, nullptr, nullptr, 768,
                    12, tid, smem, acc);
#pragma unroll
    for (int j = 0; j < 4; j++) {
      const int col = bn + wc * 64 + ((j >> 1) << 5) + ((j & 1) << 4) + (lane & 15);
      const float bs = b1ce[col];
#pragma unroll
      for (int i = 0; i < 8; i++) {
        const int row0 = bm + wr * 128 + ((i >> 2) << 6) + ((i & 3) << 4) + ((lane >> 4) << 2);
#pragma unroll
        for (int r = 0; r < 4; r++) {
          float g = gelu_exact(acc[i][j][r] + bs);
          out_ce[(size_t)(row0 + r) * 1536 + col] = f2bf(g);
        }
      }
    }
  }
}

// ---------------- fused fc2: 320 blocks of 256x256 ----------------
//   bid [0,64)    -> we: npass=2 over stacked B=[Whi;Wlo] (heavy 2x -> first)
//                    cols 0..127 = (hi+lo)*Whi + bias -> p0 ; cols 128..255 = (hi+lo)*Wlo -> p1
//   bid [64,128)  -> ew (N=128 real; upper quadrant garbage, discarded)
//   bid [128,320) -> cls (N=768)
// NOTE: ew B-tile over-reads rows 128..255 past BT2ew into adjacent workspace
// (mapped) — those columns feed only discarded accumulators.
__global__ __launch_bounds__(512, 2) void gemm2_fused(
    const u16* __restrict__ h_cls, const u16* __restrict__ hwe_hi,
    const u16* __restrict__ hwe_lo, const u16* __restrict__ BT2cls,
    const u16* __restrict__ BT2ew, const u16* __restrict__ BT2we,
    const float* __restrict__ b2cls, const float* __restrict__ b2ew,
    const float* __restrict__ b2we,
    u16* __restrict__ Lcls, u16* __restrict__ LewB,
    float* __restrict__ p0, float* __restrict__ p1) {
  __shared__ u16 smem[65536];
  const int tid = threadIdx.x;
  const int lane = tid & 63;
  const int wv = tid >> 6;
  const int wr = wv >> 2, wc = wv & 3;
  f32x4 acc[8][4];
#pragma unroll
  for (int i = 0; i < 8; i++)
#pragma unroll
    for (int j = 0; j < 4; j++) acc[i][j] = f32x4{0.f, 0.f, 0.f, 0.f};

  const int bid = blockIdx.x;
  if (bid < 64) {                          // ---- we fc2, stacked-B npass=2
    const int bm = (((bid & 7) << 3) + (bid >> 3)) << 8;
    gemm256_core<2>(hwe_hi + (size_t)bm * 768, hwe_lo + (size_t)bm * 768, nullptr, 768,
                    BT2we, BT2we, nullptr, 768, 12, tid, smem, acc);
    const int inlo = wc >> 1;              // 0: *Whi half ; 1: *Wlo half
    float* o = inlo ? p1 : p0;
    const int cb = (wc & 1) * 64;
#pragma unroll
    for (int j = 0; j < 4; j++) {
      const int col = cb + ((j >> 1) << 5) + ((j & 1) << 4) + (lane & 15);
      const float bs = inlo ? 0.f : b2we[col];
#pragma unroll
      for (int i = 0; i < 8; i++) {
        const int row0 = bm + wr * 128 + ((i >> 2) << 6) + ((i & 3) << 4) + ((lane >> 4) << 2);
#pragma unroll
        for (int r = 0; r < 4; r++)
          o[(size_t)(row0 + r) * 128 + col] = acc[i][j][r] + bs;
      }
    }
  } else if (bid < 128) {                  // ---- ew fc2 -> bf16
    const int q = bid - 64;
    const int bm = (((q & 7) << 3) + (q >> 3)) << 8;
    gemm256_core<1>(h_cls + 768 + (size_t)bm * 1536, nullptr, nullptr, 1536,
                    BT2ew, nullptr, nullptr, 768, 12, tid, smem, acc);
    if (wc < 2) {
#pragma unroll
      for (int j = 0; j < 4; j++) {
        const int col = wc * 64 + ((j >> 1) << 5) + ((j & 1) << 4) + (lane & 15);
        const float bs = b2ew[col];
#pragma unroll
        for (int i = 0; i < 8; i++) {
          const int row0 = bm + wr * 128 + ((i >> 2) << 6) + ((i & 3) << 4) + ((lane >> 4) << 2);
#pragma unroll
          for (int r = 0; r < 4; r++)
            LewB[(size_t)(row0 + r) * 128 + col] = f2bf(acc[i][j][r] + bs);
        }
      }
    }
  } else {                                 // ---- cls fc2 -> bf16
    int bm, bn;
    decode256(bid - 128, bm, bn);
    gemm256_core<1>(h_cls + (size_t)bm * 1536, nullptr, nullptr, 1536,
                    BT2cls + (size_t)bn * 768, nullptr, nullptr, 768,
                    12, tid, smem, acc);
#pragma unroll
    for (int j = 0; j < 4; j++) {
      const int col = bn + wc * 64 + ((j >> 1) << 5) + ((j & 1) << 4) + (lane & 15);
      const float bs = b2cls[col];
#pragma unroll
      for (int i = 0; i < 8; i++) {
        const int row0 = bm + wr * 128 + ((i >> 2) << 6) + ((i & 3) << 4) + ((lane >> 4) << 2);
#pragma unroll
        for (int r = 0; r < 4; r++)
          Lcls[(size_t)(row0 + r) * 768 + col] = f2bf(acc[i][j][r] + bs);
      }
    }
  }
}

// ---------------- finalize: rank-select mask (== reference threshold), softmaxes, mixture ----------------
// which_expert = p0 + p1 (f32 partials; includes the lo*Wlo refinement term).
__global__ __launch_bounds__(256) void finalize(
    const u16* __restrict__ Lcls, const float* __restrict__ p0,
    const float* __restrict__ p1, const u16* __restrict__ LewB,
    const int* __restrict__ nexp, float* __restrict__ out) {
  const int bid = blockIdx.x;
  const int g = ((bid & 7) << 9) + (bid >> 3);      // XCD band matches gemm2's row mapping
  const int b = (g << 2) + (int)(threadIdx.x >> 6); // 4 rows/block, one wave each
  const int lane = threadIdx.x & 63;
  const float NEG = -3.0e38f;
  const size_t base = (size_t)b * 128;
  const float w0 = (lane < 124) ? (p0[base + lane] + p1[base + lane]) : NEG;
  const float w1 = (lane < 60) ? (p0[base + 64 + lane] + p1[base + 64 + lane]) : NEG;
  int r0 = 0, r1 = 0;
#pragma unroll
  for (int j = 0; j < 64; ++j) {
    float v = __shfl(w0, j, 64);
    r0 += (v > w0); r1 += (v > w1);
  }
#pragma unroll
  for (int j = 0; j < 64; ++j) {
    float v = __shfl(w1, j, 64);
    r0 += (v > w0); r1 += (v > w1);
  }
  int n = nexp[b];
  n = n < 1 ? 1 : (n > 124 ? 124 : n);
  const bool k0 = (lane < 124) && (r0 < n);
  const bool k1 = (lane < 60) && (r1 < n);
  float l0 = k0 ? bf2f(LewB[base + lane]) : NEG;
  float l1 = k1 ? bf2f(LewB[base + 64 + lane]) : NEG;
  float mx = fmaxf(l0, l1);
#pragma unroll
  for (int o = 32; o > 0; o >>= 1) mx = fmaxf(mx, __shfl_xor(mx, o, 64));
  float e0 = k0 ? __expf(l0 - mx) : 0.f;
  float e1 = k1 ? __expf(l1 - mx) : 0.f;
  float S = e0 + e1;
#pragma unroll
  for (int o = 32; o > 0; o >>= 1) S += __shfl_xor(S, o, 64);
  float a0 = 0, a1 = 0, a2 = 0, a3 = 0, a4 = 0, a5 = 0;
#pragma unroll
  for (int h = 0; h < 2; ++h) {
    int e = lane + h * 64;
    float we = h ? e1 : e0;
    if (we > 0.f) {
      const u16* lp = Lcls + (size_t)b * 768 + e * 6;
      float c0 = bf2f(lp[0]), c1 = bf2f(lp[1]), c2 = bf2f(lp[2]);
      float c3 = bf2f(lp[3]), c4 = bf2f(lp[4]), c5 = bf2f(lp[5]);
      float m = fmaxf(fmaxf(fmaxf(c0, c1), fmaxf(c2, c3)), fmaxf(c4, c5));
      float q0 = __expf(c0 - m), q1 = __expf(c1 - m), q2 = __expf(c2 - m);
      float q3 = __expf(c3 - m), q4 = __expf(c4 - m), q5 = __expf(c5 - m);
      float inv = we / (q0 + q1 + q2 + q3 + q4 + q5);
      a0 += q0 * inv; a1 += q1 * inv; a2 += q2 * inv;
      a3 += q3 * inv; a4 += q4 * inv; a5 += q5 * inv;
    }
  }
#pragma unroll
  for (int o = 32; o > 0; o >>= 1) {
    a0 += __shfl_xor(a0, o, 64); a1 += __shfl_xor(a1, o, 64);
    a2 += __shfl_xor(a2, o, 64); a3 += __shfl_xor(a3, o, 64);
    a4 += __shfl_xor(a4, o, 64); a5 += __shfl_xor(a5, o, 64);
  }
  if (lane < 6) {
    float v = (lane == 0) ? a0 : (lane == 1) ? a1 : (lane == 2) ? a2
              : (lane == 3) ? a3 : (lane == 4) ? a4 : a5;
    out[(size_t)b * 6 + lane] = v / S;
  }
}

__global__ void fill_sentinel(float* out, int n, float v) {
  int i = blockIdx.x * 256 + threadIdx.x;
  if (i < n) out[i] = v;
}

extern "C" void kernel_launch(void* const* d_in, const int* in_sizes, int n_in,
                              void* d_out, int out_size, void* d_ws, size_t ws_size,
                              hipStream_t stream) {
  const float* x = (const float*)d_in[0];
  const int* nexp = (const int*)d_in[1];
  const float* cls_w1 = (const float*)d_in[2];
  const float* cls_b1 = (const float*)d_in[3];
  const float* cls_w2 = (const float*)d_in[4];
  const float* cls_b2 = (const float*)d_in[5];
  const float* we_w1 = (const float*)d_in[6];
  const float* we_b1 = (const float*)d_in[7];
  const float* we_w2 = (const float*)d_in[8];
  const float* we_b2 = (const float*)d_in[9];
  const float* ew_w1 = (const float*)d_in[10];
  const float* ew_b1 = (const float*)d_in[11];
  const float* ew_w2 = (const float*)d_in[12];
  const float* ew_b2 = (const float*)d_in[13];
  float* out = (float*)d_out;
  char* ws = (char*)d_ws;

  if (ws_size < WS_NEED) {  // diagnosable failure: absmax ~12345
    fill_sentinel<<<(out_size + 255) / 256, 256, 0, stream>>>(out, out_size, 12345.0f);
    return;
  }

  u16* xhi = (u16*)(ws + OFF_XHI);
  u16* xlo = (u16*)(ws + OFF_XLO);
  u16* Lcls = (u16*)(ws + OFF_LCLS);
  float* pwe0 = (float*)(ws + OFF_LWE_P0);
  float* pwe1 = (float*)(ws + OFF_LWE_P1);
  u16* LewB = (u16*)(ws + OFF_LEWB);
  u16* BT1 = (u16*)(ws + OFF_BT1);
  u16* BTwe_hi = (u16*)(ws + OFF_BTWE_HI);
  u16* BTwe_lo = (u16*)(ws + OFF_BTWE_LO);
  u16* BT2cls = (u16*)(ws + OFF_BT2CLS);
  u16* BT2ew = (u16*)(ws + OFF_BT2EW);
  u16* BT2we_hi = (u16*)(ws + OFF_BT2WE_HI);
  u16* BT2we_lo = (u16*)(ws + OFF_BT2WE_LO);
  float* b1ce = (float*)(ws + OFF_B1CE);
  float* b1we = (float*)(ws + OFF_B1WE);
  float* b2cls = (float*)(ws + OFF_B2CLS);
  float* b2ew = (float*)(ws + OFF_B2EW);
  float* b2we = (float*)(ws + OFF_B2WE);
  u16* h_clsew = (u16*)(ws + OFF_HCLSEW);
  u16* h_we_hi = (u16*)(ws + OFF_HWE_HI);
  u16* h_we_lo = (u16*)(ws + OFF_HWE_LO);

  prep_all<<<13165, 256, 0, stream>>>(x, xhi, xlo,
                                      cls_w1, ew_w1, we_w1, cls_w2, ew_w2, we_w2,
                                      BT1, BTwe_hi, BTwe_lo, BT2cls, BT2ew, BT2we_hi, BT2we_lo,
                                      cls_b1, ew_b1, we_b1, cls_b2, ew_b2, we_b2,
                                      b1ce, b1we, b2cls, b2ew, b2we);
  // fc1 both heads, 256^2 8-phase core; heavy npass=3 we blocks first
  gemm1_fused<<<576, 512, 0, stream>>>(xhi, xlo, BTwe_hi, BTwe_lo, BT1,
                                       b1we, b1ce, h_we_hi, h_we_lo, h_clsew);
  // fc2: we (stacked-B npass=2, heavy) first, then ew, then cls
  gemm2_fused<<<320, 512, 0, stream>>>(h_clsew, h_we_hi, h_we_lo,
                                       BT2cls, BT2ew, BT2we_hi,
                                       b2cls, b2ew, b2we,
                                       Lcls, LewB, pwe0, pwe1);
  finalize<<<4096, 256, 0, stream>>>(Lcls, pwe0, pwe1, LewB, nexp, out);
}

// Round 2
// 351.166 us; speedup vs baseline: 1.0764x; 1.0764x over previous
//
#include <hip/hip_runtime.h>
#include <stdint.h>

typedef unsigned short u16;
typedef short short8 __attribute__((ext_vector_type(8)));
typedef float f32x4 __attribute__((ext_vector_type(4)));

// Problem sizes: B=16384, D=768, E=124 (pad 128), C=6, E*C=744 (pad 768)
#define NB 16384

// ---- workspace layout (bytes) ----
#define OFF_XHI      0ull            // bf16 [16384][768]
#define OFF_XLO      25165824ull     // bf16 [16384][768]
#define OFF_LCLS     0ull            // aliases XHI: bf16 [16384][768] class logits (cols 0..743 real)
#define OFF_LWE_P0   25165824ull     // f32 [16384][128] we partial, K-half 0 (+bias)  (aliases XLO)
#define OFF_LWE_P1   33554432ull     // f32 [16384][128] we partial, K-half 1
#define OFF_BT1      50331648ull     // bf16 [1536][768]  (cls_w1^T ; ew_w1^T)  [dead after gemm1]
#define OFF_LEWB     50331648ull     // bf16 [16384][128] ew logits (aliases BT1 region, written in gemm2)
#define OFF_BTWE_HI  52690944ull     // bf16 [768][768]
#define OFF_BTWE_LO  53870592ull
#define OFF_BT2CLS   55050240ull     // bf16 [768][768] (744 real rows, padded w/ 0)
#define OFF_BT2EW    56229888ull     // bf16 [128][768]
#define OFF_BT2WE_HI 56426496ull
#define OFF_BT2WE_LO 56623104ull
#define OFF_B1CE     56819712ull     // f32 [1536]
#define OFF_B1WE     56825856ull     // f32 [768]
#define OFF_B2CLS    56828928ull     // f32 [768]
#define OFF_B2EW     56832000ull     // f32 [128]
#define OFF_B2WE     56832512ull     // f32 [128]
#define OFF_HCLSEW   56833024ull     // bf16 [16384][1536] gelu(h) for cls|ew
#define OFF_HWE_HI   107164672ull    // bf16 [16384][768]
#define OFF_HWE_LO   132330496ull    // bf16 [16384][768]
#define WS_NEED      157496320ull

__device__ __forceinline__ u16 f2bf(float f) {          // RNE f32->bf16
  uint32_t u = __float_as_uint(f);
  u += 0x7fffu + ((u >> 16) & 1u);
  return (u16)(u >> 16);
}
__device__ __forceinline__ float bf2f(u16 h) {
  return __uint_as_float(((uint32_t)h) << 16);
}
__device__ __forceinline__ void g2l16(const u16* g, u16* l) {
  // async global->LDS, 16B/lane; LDS dest = wave-uniform base + lane*16 (HW rule).
  // Global side is a normal per-lane address -> per-lane source permutation is legal.
  __builtin_amdgcn_global_load_lds(
      (__attribute__((address_space(1))) void*)(u16*)g,
      (__attribute__((address_space(3))) void*)l, 16, 0, 0);
}

// branch-free exact-GELU: 0.5*v*(1+erf(v/sqrt2)), erf via A&S 7.1.26 (|eps|<=1.5e-7).
// Validated in R1 (passed, absmax unchanged). Cheaper than libm erff in the epilogue.
__device__ __forceinline__ float gelu_exact(float v) {
  const float x = fabsf(v) * 0.70710678118654752f;
  const float t = __fdividef(1.0f, __builtin_fmaf(0.3275911f, x, 1.0f));
  float p = __builtin_fmaf(1.061405429f, t, -1.453152027f);
  p = __builtin_fmaf(p, t, 1.421413741f);
  p = __builtin_fmaf(p, t, -0.284496736f);
  p = __builtin_fmaf(p, t, 0.254829592f);
  p = p * t;
  const float e = __expf(-x * x);
  float erfx = __builtin_fmaf(-p, e, 1.0f);
  erfx = (v < 0.f) ? -erfx : erfx;
  return 0.5f * v * (1.0f + erfx);
}

// ---------------- merged prep: cvt_x split + weight transposes + bias concat ----------------
// grid layout: [0,12288) cvt_x ; [12288,13152) transpose (12x12x6) ; [13152,13165) bias
__global__ void prep_all(
    const float* __restrict__ x, u16* __restrict__ xhi, u16* __restrict__ xlo,
    const float* __restrict__ cls_w1, const float* __restrict__ ew_w1,
    const float* __restrict__ we_w1,  const float* __restrict__ cls_w2,
    const float* __restrict__ ew_w2,  const float* __restrict__ we_w2,
    u16* BT1, u16* BTwe_hi, u16* BTwe_lo,
    u16* BT2cls, u16* BT2ew, u16* BT2we_hi, u16* BT2we_lo,
    const float* __restrict__ cls_b1, const float* __restrict__ ew_b1,
    const float* __restrict__ we_b1,  const float* __restrict__ cls_b2,
    const float* __restrict__ ew_b2,  const float* __restrict__ we_b2,
    float* b1ce, float* b1we, float* b2cls, float* b2ew, float* b2we) {
  __shared__ float t[64][65];
  const int bid = blockIdx.x;
  if (bid < 12288) {                       // ---- x -> (hi,lo) bf16 split
    int i = bid * 256 + threadIdx.x;       // 12288*256 = 16384*768/4 exact
    float4 v = ((const float4*)x)[i];
    ushort4 h, l;
    h.x = f2bf(v.x); l.x = f2bf(v.x - bf2f(h.x));
    h.y = f2bf(v.y); l.y = f2bf(v.y - bf2f(h.y));
    h.z = f2bf(v.z); l.z = f2bf(v.z - bf2f(h.z));
    h.w = f2bf(v.w); l.w = f2bf(v.w - bf2f(h.w));
    ((ushort4*)xhi)[i] = h;
    ((ushort4*)xlo)[i] = l;
    return;
  }
  if (bid < 13152) {                       // ---- LDS-tiled transpose W[768][N] -> BT[Npad][768]
    const int idx = bid - 12288;
    const int bx = idx % 12, by = (idx / 12) % 12, bz = idx / 144;
    const float* src; int N; u16* dhi; u16* dlo = nullptr;
    switch (bz) {
      case 0: src = cls_w1; N = 768; dhi = BT1; break;
      case 1: src = ew_w1;  N = 768; dhi = BT1 + 768 * 768; break;
      case 2: src = we_w1;  N = 768; dhi = BTwe_hi; dlo = BTwe_lo; break;
      case 3: src = cls_w2; N = 744; dhi = BT2cls; break;
      case 4: src = ew_w2;  N = 124; dhi = BT2ew; break;
      default: src = we_w2; N = 124; dhi = BT2we_hi; dlo = BT2we_lo; break;
    }
    const int Npad = (N + 127) & ~127;
    const int n0 = by * 64;
    if (n0 >= Npad) return;
    const int k0 = bx * 64;
    const int tx = threadIdx.x & 63, tg = threadIdx.x >> 6;
#pragma unroll
    for (int r = 0; r < 16; ++r) {
      int k = tg * 16 + r;
      int n = n0 + tx;
      t[k][tx] = (n < N) ? src[(size_t)(k0 + k) * N + n] : 0.f;   // coalesced read
    }
    __syncthreads();
#pragma unroll
    for (int r = 0; r < 16; ++r) {
      int n = n0 + tg * 16 + r;
      if (n < Npad) {
        float v = t[tx][tg * 16 + r];
        u16 h = f2bf(v);
        dhi[(size_t)n * 768 + k0 + tx] = h;                       // coalesced write
        if (dlo) dlo[(size_t)n * 768 + k0 + tx] = f2bf(v - bf2f(h));
      }
    }
    return;
  }
  // ---- bias concat/pad: 13 blocks * 256 = 3328 = 1536+768+768+128+128 exact
  int id = (bid - 13152) * 256 + threadIdx.x;
  if (id < 1536) { b1ce[id] = (id < 768) ? cls_b1[id] : ew_b1[id - 768]; return; }
  id -= 1536;
  if (id < 768) { b1we[id] = we_b1[id]; return; }
  id -= 768;
  if (id < 768) { b2cls[id] = (id < 744) ? cls_b2[id] : 0.f; return; }
  id -= 768;
  if (id < 128) { b2ew[id] = (id < 124) ? ew_b2[id] : 0.f; return; }
  id -= 128;
  if (id < 128) { b2we[id] = (id < 124) ? we_b2[id] : 0.f; return; }
}

// ---------------- GEMM core (R2-exact): 128x128 tile, BK=64, 4 waves 2x2, XOR-swizzled LDS ----------------
// LDS: logical (row, c8) at physical c8p = c8 ^ (row&7) -> conflict-free ds_read_b128 (R2: 0 conflicts).
__device__ __forceinline__ void gemm_core(
    const u16* A0, const u16* A1, const u16* A2, int lda,
    const u16* B0, const u16* B1, const u16* B2,   // pre-offset by bn*K
    int npass, int K, int bm, int tid, u16* sA, u16* sB, f32x4 acc[4][4]) {
  const int lane = tid & 63;
  const int wv = tid >> 6;
  const int wr = wv >> 1, wc = wv & 1;
  const int sr = lane >> 3;                        // staging row within 8-row group
  const int sc = (((lane & 7) ^ sr) << 3);         // swizzled source col group
  for (int p = 0; p < npass; ++p) {
    const u16* A = (p == 0) ? A0 : ((p == 1) ? A1 : A2);
    const u16* Bp = (p == 0) ? B0 : ((p == 1) ? B1 : B2);
    const u16* gA = A + (size_t)(bm + wv * 32 + sr) * lda + sc;
    const u16* gB = Bp + (size_t)(wv * 32 + sr) * K + sc;
    u16* lA = sA + (wv * 32) * 64;
    u16* lB = sB + (wv * 32) * 64;
    for (int kt = 0; kt < K; kt += 64) {
#pragma unroll
      for (int s = 0; s < 4; ++s) {
        g2l16(gA + (size_t)(s * 8) * lda + kt, lA + s * 8 * 64);
        g2l16(gB + (size_t)(s * 8) * K + kt, lB + s * 8 * 64);
      }
      __syncthreads();
#pragma unroll
      for (int ks = 0; ks < 2; ++ks) {
        const int co = ((ks * 4 + (lane >> 4)) ^ (lane & 7)) * 8;  // row&7 == lane&7 for all frags
        short8 av[4], bv[4];
#pragma unroll
        for (int i = 0; i < 4; i++)
          av[i] = *(const short8*)(sA + (wr * 64 + i * 16 + (lane & 15)) * 64 + co);
#pragma unroll
        for (int j = 0; j < 4; j++)
          bv[j] = *(const short8*)(sB + (wc * 64 + j * 16 + (lane & 15)) * 64 + co);
#pragma unroll
        for (int i = 0; i < 4; i++)
#pragma unroll
          for (int j = 0; j < 4; j++)
            acc[i][j] = __builtin_amdgcn_mfma_f32_16x16x32_bf16(av[i], bv[j], acc[i][j], 0, 0, 0);
      }
      __syncthreads();
    }
  }
}

// ---------------- packed hi/lo split core: C = Ahi*Bhi^T + Alo*Bhi^T + Ahi*Blo^T, ONE K-loop ----------------
// LDS rows pack [hi(32)|lo(32)] = 128B/row -> proven XOR-8 granule swizzle unchanged; hi/lo select
// is per-lane on the global_load_lds source address. 48 MFMA per wave per barrier-pair.
// Used by gemm1's which_expert fc1 (R5-R7 proven) and now gemm2's which_expert fc2.
__device__ __forceinline__ void gemm_split_core(
    const u16* __restrict__ Ahi, const u16* __restrict__ Alo, int lda,
    const u16* __restrict__ Bhi, const u16* __restrict__ Blo, int ldb,  // pre-offset to tile row 0
    int K, int bm, int tid, u16* sA, u16* sB, f32x4 acc[4][4]) {
  const int lane = tid & 63;
  const int wv = tid >> 6;
  const int wr = wv >> 1, wc = wv & 1;
  const int sr = lane >> 3;                  // row within 8-row staging group
  const int gl = (lane & 7) ^ sr;            // logical granule at this lane's phys slot
  const int koff = (gl & 3) << 3;            // element offset within the 32-elem half
  const u16* Asel = (gl < 4) ? Ahi : Alo;
  const u16* Bsel = (gl < 4) ? Bhi : Blo;
  const u16* gA = Asel + (size_t)(bm + wv * 32 + sr) * lda + koff;
  const u16* gB = Bsel + (size_t)(wv * 32 + sr) * ldb + koff;
  u16* lA = sA + (wv * 32) * 64;
  u16* lB = sB + (wv * 32) * 64;

  for (int kt = 0; kt < K; kt += 32) {
#pragma unroll
    for (int s = 0; s < 4; ++s) {
      g2l16(gA + (size_t)(s * 8) * lda + kt, lA + s * 8 * 64);
      g2l16(gB + (size_t)(s * 8) * ldb + kt, lB + s * 8 * 64);
    }
    __syncthreads();
    // fragment granule: hi at (kg ^ row&7), lo at same ^ 4 -> element offset ^32
    const int coh = (((lane >> 4) ^ (lane & 7)) << 3);
    short8 ah[4], al[4], bh[4], bl[4];
#pragma unroll
    for (int i = 0; i < 4; i++) {
      const u16* p = sA + (wr * 64 + i * 16 + (lane & 15)) * 64;
      ah[i] = *(const short8*)(p + coh);
      al[i] = *(const short8*)(p + (coh ^ 32));
    }
#pragma unroll
    for (int j = 0; j < 4; j++) {
      const u16* p = sB + (wc * 64 + j * 16 + (lane & 15)) * 64;
      bh[j] = *(const short8*)(p + coh);
      bl[j] = *(const short8*)(p + (coh ^ 32));
    }
#pragma unroll
    for (int i = 0; i < 4; i++)
#pragma unroll
      for (int j = 0; j < 4; j++) {
        acc[i][j] = __builtin_amdgcn_mfma_f32_16x16x32_bf16(ah[i], bh[j], acc[i][j], 0, 0, 0);
        acc[i][j] = __builtin_amdgcn_mfma_f32_16x16x32_bf16(al[i], bh[j], acc[i][j], 0, 0, 0);
        acc[i][j] = __builtin_amdgcn_mfma_f32_16x16x32_bf16(ah[i], bl[j], acc[i][j], 0, 0, 0);
      }
    __syncthreads();
  }
}

// XCD/L2 swizzle for 128-row tiles: xcd=bid&7 owns 16 row-chunks; 8-row sub-bands, rows fastest.
__device__ __forceinline__ void decode_bid(int bid, int NC, int& bm, int& bn) {
  const int xcd = bid & 7, slot = bid >> 3;
  const int per = NC << 3;
  const int sub = slot / per, rem = slot - sub * per;
  const int colu = rem >> 3, rowIn = rem & 7;
  bm = ((xcd << 4) + (sub << 3) + rowIn) << 7;
  bn = colu << 7;
}

// ---------------- fused fc1: BOTH heads in one dispatch ----------------
// bid [0,768)    -> which_expert packed-split GEMM (heavy ~3x -> first)
// bid [768,2304) -> cls+ew GEMM (light, backfills residency gaps + tail)
__global__ __launch_bounds__(256, 4) void gemm1_fused(
    const u16* __restrict__ Ahi, const u16* __restrict__ Alo,      // xhi, xlo [16384][768]
    const u16* __restrict__ Bwe_hi, const u16* __restrict__ Bwe_lo,// we_w1^T splits [768][768]
    const u16* __restrict__ BT1,                                   // [cls_w1^T; ew_w1^T] [1536][768]
    const float* __restrict__ b1we, const float* __restrict__ b1ce,
    u16* __restrict__ out_we_hi, u16* __restrict__ out_we_lo,      // [16384][768]
    u16* __restrict__ out_ce) {                                    // [16384][1536]
  __shared__ u16 smem[2 * 128 * 64];
  u16* sA = smem;
  u16* sB = smem + 128 * 64;
  const int tid = threadIdx.x;
  const int lane = tid & 63;
  const int wr = (tid >> 6) >> 1, wc = (tid >> 6) & 1;
  const int K = 768;

  f32x4 acc[4][4];
#pragma unroll
  for (int i = 0; i < 4; i++)
#pragma unroll
    for (int j = 0; j < 4; j++) acc[i][j] = f32x4{0.f, 0.f, 0.f, 0.f};

  if (blockIdx.x < 768) {
    // ===== which_expert fc1: packed-split, gelu -> bf16 hi + lo =====
    int bm, bn;
    decode_bid(blockIdx.x, 6, bm, bn);
    gemm_split_core(Ahi, Alo, K, Bwe_hi + (size_t)bn * K, Bwe_lo + (size_t)bn * K, K,
                    K, bm, tid, sA, sB, acc);
#pragma unroll
    for (int j = 0; j < 4; j++) {
      const int col = bn + wc * 64 + j * 16 + (lane & 15);
      const float bs = b1we[col];
#pragma unroll
      for (int i = 0; i < 4; i++) {
        const int row0 = bm + wr * 64 + i * 16 + (lane >> 4) * 4;
#pragma unroll
        for (int r = 0; r < 4; r++) {
          float g = gelu_exact(acc[i][j][r] + bs);
          const size_t idx = (size_t)(row0 + r) * 768 + col;
          u16 h = f2bf(g);
          out_we_hi[idx] = h;
          out_we_lo[idx] = f2bf(g - bf2f(h));
        }
      }
    }
  } else {
    // ===== cls+ew fc1 (N=1536), gelu -> bf16 =====
    int bm, bn;
    decode_bid(blockIdx.x - 768, 12, bm, bn);
    gemm_core(Ahi, nullptr, nullptr, 768, BT1 + (size_t)bn * K, nullptr, nullptr,
              1, K, bm, tid, sA, sB, acc);
#pragma unroll
    for (int j = 0; j < 4; j++) {
      const int col = bn + wc * 64 + j * 16 + (lane & 15);
      const float bs = b1ce[col];
#pragma unroll
      for (int i = 0; i < 4; i++) {
        const int row0 = bm + wr * 64 + i * 16 + (lane >> 4) * 4;
#pragma unroll
        for (int r = 0; r < 4; r++) {
          float g = gelu_exact(acc[i][j][r] + bs);
          out_ce[(size_t)(row0 + r) * 1536 + col] = f2bf(g);
        }
      }
    }
  }
}

// fused fc2, new block plan (R2 of this session):
//   bid [0,256)     -> we packed-split half-K blocks (heavy 1.5u -> first):
//                      half = bid>>7, row-chunk r = bid&127; K-range [half*384, half*384+384)
//                      acc = hi*Whi + lo*Whi + hi*Wlo over that K-half -> f32 partial p{half}
//                      (48 MFMA/barrier-pair vs 32 for the old 3-pass plan; hi-A read once)
//   bid [256,1024)  -> cls (1u, 12 K-tiles)
//   bid [1024,1152) -> ew  (1u) -> bf16 Lew   (last: backfills the drain)
//   (bid&7 XCD band preserved for all groups -> row-chunk passes share an XCD's L2)
__global__ __launch_bounds__(256, 4) void gemm2_fused(
    const u16* __restrict__ h_cls,                  // [16384][1536]: cls cols 0..767, ew cols 768..1535
    const u16* __restrict__ hwe_hi, const u16* __restrict__ hwe_lo,
    const u16* __restrict__ BT2cls, const u16* __restrict__ BT2ew,
    const u16* __restrict__ BT2we_hi, const u16* __restrict__ BT2we_lo,
    const float* __restrict__ b2cls, const float* __restrict__ b2ew,
    const float* __restrict__ b2we,
    u16* __restrict__ Lcls, u16* __restrict__ LewB,
    float* __restrict__ p0, float* __restrict__ p1) {
  __shared__ u16 sA[128 * 64];
  __shared__ u16 sB[128 * 64];
  const int tid = threadIdx.x;
  const int lane = tid & 63;
  const int wr = (tid >> 6) >> 1, wc = (tid >> 6) & 1;

  f32x4 acc[4][4];
#pragma unroll
  for (int i = 0; i < 4; i++)
#pragma unroll
    for (int j = 0; j < 4; j++) acc[i][j] = f32x4{0.f, 0.f, 0.f, 0.f};

  const int bid = blockIdx.x;
  if (bid < 256) {                         // ---- we fc2: packed-split, half-K
    const int half = bid >> 7;
    const int r = bid & 127;
    const int bm = (((r & 7) << 4) + (r >> 3)) << 7;
    const int k0 = half * 384;
    gemm_split_core(hwe_hi + k0, hwe_lo + k0, 768,
                    BT2we_hi + k0, BT2we_lo + k0, 768,
                    384, bm, tid, sA, sB, acc);
    float* o = half ? p1 : p0;
#pragma unroll
    for (int j = 0; j < 4; j++) {
      const int col = wc * 64 + j * 16 + (lane & 15);
      const float bs = half ? 0.f : b2we[col];          // bias counted once (half 0)
#pragma unroll
      for (int i = 0; i < 4; i++) {
        const int row0 = bm + wr * 64 + i * 16 + (lane >> 4) * 4;
#pragma unroll
        for (int r2 = 0; r2 < 4; r2++)
          o[(size_t)(row0 + r2) * 128 + col] = acc[i][j][r2] + bs;
      }
    }
  } else if (bid < 1024) {                 // ---- cls: 6 col-tiles
    int bm, bn;
    decode_bid(bid - 256, 6, bm, bn);
    gemm_core(h_cls, nullptr, nullptr, 1536, BT2cls + (size_t)bn * 768, nullptr, nullptr,
              1, 768, bm, tid, sA, sB, acc);
#pragma unroll
    for (int j = 0; j < 4; j++) {
      const int col = bn + wc * 64 + j * 16 + (lane & 15);
      const float bs = b2cls[col];
#pragma unroll
      for (int i = 0; i < 4; i++) {
        const int row0 = bm + wr * 64 + i * 16 + (lane >> 4) * 4;
#pragma unroll
        for (int r = 0; r < 4; r++)
          Lcls[(size_t)(row0 + r) * 768 + col] = f2bf(acc[i][j][r] + bs);
      }
    }
  } else {                                 // ---- ew (K=768 from h cols 768..1535) -> bf16
    const int r = bid - 1024;
    const int bm = (((r & 7) << 4) + (r >> 3)) << 7;
    gemm_core(h_cls + 768, nullptr, nullptr, 1536, BT2ew, nullptr, nullptr,
              1, 768, bm, tid, sA, sB, acc);
#pragma unroll
    for (int j = 0; j < 4; j++) {
      const int col = wc * 64 + j * 16 + (lane & 15);
      const float bs = b2ew[col];
#pragma unroll
      for (int i = 0; i < 4; i++) {
        const int row0 = bm + wr * 64 + i * 16 + (lane >> 4) * 4;
#pragma unroll
        for (int r2 = 0; r2 < 4; r2++)
          LewB[(size_t)(row0 + r2) * 128 + col] = f2bf(acc[i][j][r2] + bs);
      }
    }
  }
}

// ---------------- finalize: rank-select mask (== reference threshold), softmaxes, mixture ----------------
// which_expert = p0 + p1 (deterministic f32 sum of the two K-half partials).
// keep_i  <=>  which_i >= n-th largest  <=>  #{j : w_j > w_i} < n   (ties keep both, same as ref)
__global__ __launch_bounds__(256) void finalize(
    const u16* __restrict__ Lcls,   // bf16 [B][768], expert e at cols e*6..e*6+5
    const float* __restrict__ p0, const float* __restrict__ p1,
    const u16* __restrict__ LewB,   // bf16 [B][128]
    const int* __restrict__ nexp, float* __restrict__ out) {
  const int bid = blockIdx.x;
  const int g = ((bid & 7) << 9) + (bid >> 3);      // XCD band matches gemm2's row mapping
  const int b = (g << 2) + (int)(threadIdx.x >> 6); // 4 rows/block, one wave each
  const int lane = threadIdx.x & 63;
  const float NEG = -3.0e38f;
  const size_t base = (size_t)b * 128;
  const float w0 = (lane < 124) ? (p0[base + lane] + p1[base + lane]) : NEG;
  const float w1 = (lane < 60) ? (p0[base + 64 + lane] + p1[base + 64 + lane]) : NEG;
  int r0 = 0, r1 = 0;
#pragma unroll
  for (int j = 0; j < 64; ++j) {
    float v = __shfl(w0, j, 64);
    r0 += (v > w0); r1 += (v > w1);
  }
#pragma unroll
  for (int j = 0; j < 64; ++j) {
    float v = __shfl(w1, j, 64);
    r0 += (v > w0); r1 += (v > w1);
  }
  int n = nexp[b];
  n = n < 1 ? 1 : (n > 124 ? 124 : n);
  const bool k0 = (lane < 124) && (r0 < n);
  const bool k1 = (lane < 60) && (r1 < n);
  float l0 = k0 ? bf2f(LewB[base + lane]) : NEG;
  float l1 = k1 ? bf2f(LewB[base + 64 + lane]) : NEG;
  float mx = fmaxf(l0, l1);
#pragma unroll
  for (int o = 32; o > 0; o >>= 1) mx = fmaxf(mx, __shfl_xor(mx, o, 64));
  float e0 = k0 ? __expf(l0 - mx) : 0.f;
  float e1 = k1 ? __expf(l1 - mx) : 0.f;
  float S = e0 + e1;
#pragma unroll
  for (int o = 32; o > 0; o >>= 1) S += __shfl_xor(S, o, 64);
  float a0 = 0, a1 = 0, a2 = 0, a3 = 0, a4 = 0, a5 = 0;
#pragma unroll
  for (int h = 0; h < 2; ++h) {
    int e = lane + h * 64;
    float we = h ? e1 : e0;
    if (we > 0.f) {
      const u16* lp = Lcls + (size_t)b * 768 + e * 6;
      float c0 = bf2f(lp[0]), c1 = bf2f(lp[1]), c2 = bf2f(lp[2]);
      float c3 = bf2f(lp[3]), c4 = bf2f(lp[4]), c5 = bf2f(lp[5]);
      float m = fmaxf(fmaxf(fmaxf(c0, c1), fmaxf(c2, c3)), fmaxf(c4, c5));
      float q0 = __expf(c0 - m), q1 = __expf(c1 - m), q2 = __expf(c2 - m);
      float q3 = __expf(c3 - m), q4 = __expf(c4 - m), q5 = __expf(c5 - m);
      float inv = we / (q0 + q1 + q2 + q3 + q4 + q5);
      a0 += q0 * inv; a1 += q1 * inv; a2 += q2 * inv;
      a3 += q3 * inv; a4 += q4 * inv; a5 += q5 * inv;
    }
  }
#pragma unroll
  for (int o = 32; o > 0; o >>= 1) {
    a0 += __shfl_xor(a0, o, 64); a1 += __shfl_xor(a1, o, 64);
    a2 += __shfl_xor(a2, o, 64); a3 += __shfl_xor(a3, o, 64);
    a4 += __shfl_xor(a4, o, 64); a5 += __shfl_xor(a5, o, 64);
  }
  if (lane < 6) {
    float v = (lane == 0) ? a0 : (lane == 1) ? a1 : (lane == 2) ? a2
              : (lane == 3) ? a3 : (lane == 4) ? a4 : a5;
    out[(size_t)b * 6 + lane] = v / S;
  }
}

__global__ void fill_sentinel(float* out, int n, float v) {
  int i = blockIdx.x * 256 + threadIdx.x;
  if (i < n) out[i] = v;
}

extern "C" void kernel_launch(void* const* d_in, const int* in_sizes, int n_in,
                              void* d_out, int out_size, void* d_ws, size_t ws_size,
                              hipStream_t stream) {
  const float* x = (const float*)d_in[0];
  const int* nexp = (const int*)d_in[1];
  const float* cls_w1 = (const float*)d_in[2];
  const float* cls_b1 = (const float*)d_in[3];
  const float* cls_w2 = (const float*)d_in[4];
  const float* cls_b2 = (const float*)d_in[5];
  const float* we_w1 = (const float*)d_in[6];
  const float* we_b1 = (const float*)d_in[7];
  const float* we_w2 = (const float*)d_in[8];
  const float* we_b2 = (const float*)d_in[9];
  const float* ew_w1 = (const float*)d_in[10];
  const float* ew_b1 = (const float*)d_in[11];
  const float* ew_w2 = (const float*)d_in[12];
  const float* ew_b2 = (const float*)d_in[13];
  float* out = (float*)d_out;
  char* ws = (char*)d_ws;

  if (ws_size < WS_NEED) {  // diagnosable failure: absmax ~12345
    fill_sentinel<<<(out_size + 255) / 256, 256, 0, stream>>>(out, out_size, 12345.0f);
    return;
  }

  u16* xhi = (u16*)(ws + OFF_XHI);
  u16* xlo = (u16*)(ws + OFF_XLO);
  u16* Lcls = (u16*)(ws + OFF_LCLS);
  float* pwe0 = (float*)(ws + OFF_LWE_P0);
  float* pwe1 = (float*)(ws + OFF_LWE_P1);
  u16* LewB = (u16*)(ws + OFF_LEWB);
  u16* BT1 = (u16*)(ws + OFF_BT1);
  u16* BTwe_hi = (u16*)(ws + OFF_BTWE_HI);
  u16* BTwe_lo = (u16*)(ws + OFF_BTWE_LO);
  u16* BT2cls = (u16*)(ws + OFF_BT2CLS);
  u16* BT2ew = (u16*)(ws + OFF_BT2EW);
  u16* BT2we_hi = (u16*)(ws + OFF_BT2WE_HI);
  u16* BT2we_lo = (u16*)(ws + OFF_BT2WE_LO);
  float* b1ce = (float*)(ws + OFF_B1CE);
  float* b1we = (float*)(ws + OFF_B1WE);
  float* b2cls = (float*)(ws + OFF_B2CLS);
  float* b2ew = (float*)(ws + OFF_B2EW);
  float* b2we = (float*)(ws + OFF_B2WE);
  u16* h_clsew = (u16*)(ws + OFF_HCLSEW);
  u16* h_we_hi = (u16*)(ws + OFF_HWE_HI);
  u16* h_we_lo = (u16*)(ws + OFF_HWE_LO);

  prep_all<<<13165, 256, 0, stream>>>(x, xhi, xlo,
                                      cls_w1, ew_w1, we_w1, cls_w2, ew_w2, we_w2,
                                      BT1, BTwe_hi, BTwe_lo, BT2cls, BT2ew, BT2we_hi, BT2we_lo,
                                      cls_b1, ew_b1, we_b1, cls_b2, ew_b2, we_b2,
                                      b1ce, b1we, b2cls, b2ew, b2we);
  // fc1 BOTH heads in one dispatch: heavy packed-split we blocks first, cls/ew backfills
  gemm1_fused<<<2304, 256, 0, stream>>>(xhi, xlo, BTwe_hi, BTwe_lo, BT1,
                                        b1we, b1ce, h_we_hi, h_we_lo, h_clsew);
  // fc2: 1152 blocks; we packed-split half-K (1.5u) first, cls (1u), ew (1u) backfills drain
  gemm2_fused<<<1152, 256, 0, stream>>>(h_clsew, h_we_hi, h_we_lo,
                                        BT2cls, BT2ew, BT2we_hi, BT2we_lo,
                                        b2cls, b2ew, b2we,
                                        Lcls, LewB, pwe0, pwe1);
  finalize<<<4096, 256, 0, stream>>>(Lcls, pwe0, pwe1, LewB, nexp, out);
}

// Round 3
// 337.637 us; speedup vs baseline: 1.1195x; 1.0401x over previous
//
#include <hip/hip_runtime.h>
#include <stdint.h>

typedef unsigned short u16;
typedef short short8 __attribute__((ext_vector_type(8)));
typedef float f32x4 __attribute__((ext_vector_type(4)));

// Problem sizes: B=16384, D=768, E=124 (pad 128), C=6, E*C=744 (pad 768)
#define NB 16384

// ---- workspace layout (bytes) ----
#define OFF_XHI      0ull            // bf16 [16384][768]
#define OFF_XLO      25165824ull     // bf16 [16384][768]
#define OFF_LCLS     0ull            // aliases XHI: bf16 [16384][768] class logits (cols 0..743 real)
#define OFF_LWE_P0   25165824ull     // f32 [16384][128] we partial, K-half 0 (+bias)  (aliases XLO)
#define OFF_LWE_P1   33554432ull     // f32 [16384][128] we partial, K-half 1
#define OFF_BT1      50331648ull     // bf16 [1536][768]  (cls_w1^T ; ew_w1^T)  [dead after gemm1]
#define OFF_LEWB     50331648ull     // bf16 [16384][128] ew logits (aliases BT1 region, written in gemm2)
#define OFF_BTWE_HI  52690944ull     // bf16 [768][768]
#define OFF_BTWE_LO  53870592ull
#define OFF_BT2CLS   55050240ull     // bf16 [768][768] (744 real rows, padded w/ 0)
#define OFF_BT2EW    56229888ull     // bf16 [128][768]
#define OFF_BT2WE_HI 56426496ull
#define OFF_BT2WE_LO 56623104ull
#define OFF_B1CE     56819712ull     // f32 [1536]
#define OFF_B1WE     56825856ull     // f32 [768]
#define OFF_B2CLS    56828928ull     // f32 [768]
#define OFF_B2EW     56832000ull     // f32 [128]
#define OFF_B2WE     56832512ull     // f32 [128]
#define OFF_HCLSEW   56833024ull     // bf16 [16384][1536] gelu(h) for cls|ew
#define OFF_HWE_HI   107164672ull    // bf16 [16384][768]
#define OFF_HWE_LO   132330496ull    // bf16 [16384][768]
#define WS_NEED      157496320ull

__device__ __forceinline__ u16 f2bf(float f) {          // RNE f32->bf16
  uint32_t u = __float_as_uint(f);
  u += 0x7fffu + ((u >> 16) & 1u);
  return (u16)(u >> 16);
}
__device__ __forceinline__ float bf2f(u16 h) {
  return __uint_as_float(((uint32_t)h) << 16);
}
__device__ __forceinline__ uint32_t pk2(float a, float b) {   // pack 2 bf16 into u32
  return (uint32_t)f2bf(a) | ((uint32_t)f2bf(b) << 16);
}
__device__ __forceinline__ void g2l16(const u16* g, u16* l) {
  // async global->LDS, 16B/lane; LDS dest = wave-uniform base + lane*16 (HW rule).
  // Global side is a normal per-lane address -> per-lane source permutation is legal.
  __builtin_amdgcn_global_load_lds(
      (__attribute__((address_space(1))) void*)(u16*)g,
      (__attribute__((address_space(3))) void*)l, 16, 0, 0);
}

// branch-free exact-GELU: 0.5*v*(1+erf(v/sqrt2)), erf via A&S 7.1.26 (|eps|<=1.5e-7).
__device__ __forceinline__ float gelu_exact(float v) {
  const float x = fabsf(v) * 0.70710678118654752f;
  const float t = __fdividef(1.0f, __builtin_fmaf(0.3275911f, x, 1.0f));
  float p = __builtin_fmaf(1.061405429f, t, -1.453152027f);
  p = __builtin_fmaf(p, t, 1.421413741f);
  p = __builtin_fmaf(p, t, -0.284496736f);
  p = __builtin_fmaf(p, t, 0.254829592f);
  p = p * t;
  const float e = __expf(-x * x);
  float erfx = __builtin_fmaf(-p, e, 1.0f);
  erfx = (v < 0.f) ? -erfx : erfx;
  return 0.5f * v * (1.0f + erfx);
}

// ---------------- merged prep: cvt_x split + weight transposes + bias concat ----------------
// grid layout: [0,12288) cvt_x ; [12288,13152) transpose (12x12x6) ; [13152,13165) bias
__global__ void prep_all(
    const float* __restrict__ x, u16* __restrict__ xhi, u16* __restrict__ xlo,
    const float* __restrict__ cls_w1, const float* __restrict__ ew_w1,
    const float* __restrict__ we_w1,  const float* __restrict__ cls_w2,
    const float* __restrict__ ew_w2,  const float* __restrict__ we_w2,
    u16* BT1, u16* BTwe_hi, u16* BTwe_lo,
    u16* BT2cls, u16* BT2ew, u16* BT2we_hi, u16* BT2we_lo,
    const float* __restrict__ cls_b1, const float* __restrict__ ew_b1,
    const float* __restrict__ we_b1,  const float* __restrict__ cls_b2,
    const float* __restrict__ ew_b2,  const float* __restrict__ we_b2,
    float* b1ce, float* b1we, float* b2cls, float* b2ew, float* b2we) {
  __shared__ float t[64][65];
  const int bid = blockIdx.x;
  if (bid < 12288) {                       // ---- x -> (hi,lo) bf16 split
    int i = bid * 256 + threadIdx.x;       // 12288*256 = 16384*768/4 exact
    float4 v = ((const float4*)x)[i];
    ushort4 h, l;
    h.x = f2bf(v.x); l.x = f2bf(v.x - bf2f(h.x));
    h.y = f2bf(v.y); l.y = f2bf(v.y - bf2f(h.y));
    h.z = f2bf(v.z); l.z = f2bf(v.z - bf2f(h.z));
    h.w = f2bf(v.w); l.w = f2bf(v.w - bf2f(h.w));
    ((ushort4*)xhi)[i] = h;
    ((ushort4*)xlo)[i] = l;
    return;
  }
  if (bid < 13152) {                       // ---- LDS-tiled transpose W[768][N] -> BT[Npad][768]
    const int idx = bid - 12288;
    const int bx = idx % 12, by = (idx / 12) % 12, bz = idx / 144;
    const float* src; int N; u16* dhi; u16* dlo = nullptr;
    switch (bz) {
      case 0: src = cls_w1; N = 768; dhi = BT1; break;
      case 1: src = ew_w1;  N = 768; dhi = BT1 + 768 * 768; break;
      case 2: src = we_w1;  N = 768; dhi = BTwe_hi; dlo = BTwe_lo; break;
      case 3: src = cls_w2; N = 744; dhi = BT2cls; break;
      case 4: src = ew_w2;  N = 124; dhi = BT2ew; break;
      default: src = we_w2; N = 124; dhi = BT2we_hi; dlo = BT2we_lo; break;
    }
    const int Npad = (N + 127) & ~127;
    const int n0 = by * 64;
    if (n0 >= Npad) return;
    const int k0 = bx * 64;
    const int tx = threadIdx.x & 63, tg = threadIdx.x >> 6;
#pragma unroll
    for (int r = 0; r < 16; ++r) {
      int k = tg * 16 + r;
      int n = n0 + tx;
      t[k][tx] = (n < N) ? src[(size_t)(k0 + k) * N + n] : 0.f;   // coalesced read
    }
    __syncthreads();
#pragma unroll
    for (int r = 0; r < 16; ++r) {
      int n = n0 + tg * 16 + r;
      if (n < Npad) {
        float v = t[tx][tg * 16 + r];
        u16 h = f2bf(v);
        dhi[(size_t)n * 768 + k0 + tx] = h;                       // coalesced write
        if (dlo) dlo[(size_t)n * 768 + k0 + tx] = f2bf(v - bf2f(h));
      }
    }
    return;
  }
  // ---- bias concat/pad: 13 blocks * 256 = 3328 = 1536+768+768+128+128 exact
  int id = (bid - 13152) * 256 + threadIdx.x;
  if (id < 1536) { b1ce[id] = (id < 768) ? cls_b1[id] : ew_b1[id - 768]; return; }
  id -= 1536;
  if (id < 768) { b1we[id] = we_b1[id]; return; }
  id -= 768;
  if (id < 768) { b2cls[id] = (id < 744) ? cls_b2[id] : 0.f; return; }
  id -= 768;
  if (id < 128) { b2ew[id] = (id < 124) ? ew_b2[id] : 0.f; return; }
  id -= 128;
  if (id < 128) { b2we[id] = (id < 124) ? we_b2[id] : 0.f; return; }
}

// ---------------- GEMM core: 128x128 tile, BK=64, 4 waves 2x2, XOR-swizzled LDS ----------------
// LDS: logical (row, c8) at physical c8p = c8 ^ (row&7) -> conflict-free ds_read_b128 (0 conflicts).
// MFMA operands SWAPPED (bv, av) -> acc holds C^T fragments: lane owns ONE row (lane&15 within
// frag) and 4 CONSECUTIVE cols ((lane>>4)*4 + r). Enables packed dwordx2/dwordx4 epilogue stores.
__device__ __forceinline__ void gemm_core(
    const u16* A0, const u16* A1, const u16* A2, int lda,
    const u16* B0, const u16* B1, const u16* B2,   // pre-offset by bn*K
    int npass, int K, int bm, int tid, u16* sA, u16* sB, f32x4 acc[4][4]) {
  const int lane = tid & 63;
  const int wv = tid >> 6;
  const int wr = wv >> 1, wc = wv & 1;
  const int sr = lane >> 3;                        // staging row within 8-row group
  const int sc = (((lane & 7) ^ sr) << 3);         // swizzled source col group
  for (int p = 0; p < npass; ++p) {
    const u16* A = (p == 0) ? A0 : ((p == 1) ? A1 : A2);
    const u16* Bp = (p == 0) ? B0 : ((p == 1) ? B1 : B2);
    const u16* gA = A + (size_t)(bm + wv * 32 + sr) * lda + sc;
    const u16* gB = Bp + (size_t)(wv * 32 + sr) * K + sc;
    u16* lA = sA + (wv * 32) * 64;
    u16* lB = sB + (wv * 32) * 64;
    for (int kt = 0; kt < K; kt += 64) {
#pragma unroll
      for (int s = 0; s < 4; ++s) {
        g2l16(gA + (size_t)(s * 8) * lda + kt, lA + s * 8 * 64);
        g2l16(gB + (size_t)(s * 8) * K + kt, lB + s * 8 * 64);
      }
      __syncthreads();
#pragma unroll
      for (int ks = 0; ks < 2; ++ks) {
        const int co = ((ks * 4 + (lane >> 4)) ^ (lane & 7)) * 8;  // row&7 == lane&7 for all frags
        short8 av[4], bv[4];
#pragma unroll
        for (int i = 0; i < 4; i++)
          av[i] = *(const short8*)(sA + (wr * 64 + i * 16 + (lane & 15)) * 64 + co);
#pragma unroll
        for (int j = 0; j < 4; j++)
          bv[j] = *(const short8*)(sB + (wc * 64 + j * 16 + (lane & 15)) * 64 + co);
#pragma unroll
        for (int i = 0; i < 4; i++)
#pragma unroll
          for (int j = 0; j < 4; j++)
            acc[i][j] = __builtin_amdgcn_mfma_f32_16x16x32_bf16(bv[j], av[i], acc[i][j], 0, 0, 0);
      }
      __syncthreads();
    }
  }
}

// ---------------- packed hi/lo split core: C = Ahi*Bhi^T + Alo*Bhi^T + Ahi*Blo^T, ONE K-loop ----------------
// LDS rows pack [hi(32)|lo(32)] = 128B/row -> proven XOR-8 granule swizzle unchanged; hi/lo select
// is per-lane on the global_load_lds source address. 48 MFMA per wave per barrier-pair.
// MFMA operands swapped (C^T fragments) like gemm_core.
__device__ __forceinline__ void gemm_split_core(
    const u16* __restrict__ Ahi, const u16* __restrict__ Alo, int lda,
    const u16* __restrict__ Bhi, const u16* __restrict__ Blo, int ldb,  // pre-offset to tile row 0
    int K, int bm, int tid, u16* sA, u16* sB, f32x4 acc[4][4]) {
  const int lane = tid & 63;
  const int wv = tid >> 6;
  const int wr = wv >> 1, wc = wv & 1;
  const int sr = lane >> 3;                  // row within 8-row staging group
  const int gl = (lane & 7) ^ sr;            // logical granule at this lane's phys slot
  const int koff = (gl & 3) << 3;            // element offset within the 32-elem half
  const u16* Asel = (gl < 4) ? Ahi : Alo;
  const u16* Bsel = (gl < 4) ? Bhi : Blo;
  const u16* gA = Asel + (size_t)(bm + wv * 32 + sr) * lda + koff;
  const u16* gB = Bsel + (size_t)(wv * 32 + sr) * ldb + koff;
  u16* lA = sA + (wv * 32) * 64;
  u16* lB = sB + (wv * 32) * 64;

  for (int kt = 0; kt < K; kt += 32) {
#pragma unroll
    for (int s = 0; s < 4; ++s) {
      g2l16(gA + (size_t)(s * 8) * lda + kt, lA + s * 8 * 64);
      g2l16(gB + (size_t)(s * 8) * ldb + kt, lB + s * 8 * 64);
    }
    __syncthreads();
    // fragment granule: hi at (kg ^ row&7), lo at same ^ 4 -> element offset ^32
    const int coh = (((lane >> 4) ^ (lane & 7)) << 3);
    short8 ah[4], al[4], bh[4], bl[4];
#pragma unroll
    for (int i = 0; i < 4; i++) {
      const u16* p = sA + (wr * 64 + i * 16 + (lane & 15)) * 64;
      ah[i] = *(const short8*)(p + coh);
      al[i] = *(const short8*)(p + (coh ^ 32));
    }
#pragma unroll
    for (int j = 0; j < 4; j++) {
      const u16* p = sB + (wc * 64 + j * 16 + (lane & 15)) * 64;
      bh[j] = *(const short8*)(p + coh);
      bl[j] = *(const short8*)(p + (coh ^ 32));
    }
#pragma unroll
    for (int i = 0; i < 4; i++)
#pragma unroll
      for (int j = 0; j < 4; j++) {
        acc[i][j] = __builtin_amdgcn_mfma_f32_16x16x32_bf16(bh[j], ah[i], acc[i][j], 0, 0, 0);
        acc[i][j] = __builtin_amdgcn_mfma_f32_16x16x32_bf16(bh[j], al[i], acc[i][j], 0, 0, 0);
        acc[i][j] = __builtin_amdgcn_mfma_f32_16x16x32_bf16(bl[j], ah[i], acc[i][j], 0, 0, 0);
      }
    __syncthreads();
  }
}

// XCD/L2 swizzle for 128-row tiles: xcd=bid&7 owns 16 row-chunks; 8-row sub-bands, rows fastest.
__device__ __forceinline__ void decode_bid(int bid, int NC, int& bm, int& bn) {
  const int xcd = bid & 7, slot = bid >> 3;
  const int per = NC << 3;
  const int sub = slot / per, rem = slot - sub * per;
  const int colu = rem >> 3, rowIn = rem & 7;
  bm = ((xcd << 4) + (sub << 3) + rowIn) << 7;
  bn = colu << 7;
}

// ---------------- fused fc1: BOTH heads in one dispatch ----------------
// bid [0,768)    -> which_expert packed-split GEMM (heavy ~3x -> first)
// bid [768,2304) -> cls+ew GEMM (light, backfills residency gaps + tail)
__global__ __launch_bounds__(256, 4) void gemm1_fused(
    const u16* __restrict__ Ahi, const u16* __restrict__ Alo,      // xhi, xlo [16384][768]
    const u16* __restrict__ Bwe_hi, const u16* __restrict__ Bwe_lo,// we_w1^T splits [768][768]
    const u16* __restrict__ BT1,                                   // [cls_w1^T; ew_w1^T] [1536][768]
    const float* __restrict__ b1we, const float* __restrict__ b1ce,
    u16* __restrict__ out_we_hi, u16* __restrict__ out_we_lo,      // [16384][768]
    u16* __restrict__ out_ce) {                                    // [16384][1536]
  __shared__ u16 smem[2 * 128 * 64];
  u16* sA = smem;
  u16* sB = smem + 128 * 64;
  const int tid = threadIdx.x;
  const int lane = tid & 63;
  const int wr = (tid >> 6) >> 1, wc = (tid >> 6) & 1;
  const int K = 768;

  f32x4 acc[4][4];
#pragma unroll
  for (int i = 0; i < 4; i++)
#pragma unroll
    for (int j = 0; j < 4; j++) acc[i][j] = f32x4{0.f, 0.f, 0.f, 0.f};

  if (blockIdx.x < 768) {
    // ===== which_expert fc1: packed-split, gelu -> bf16 hi + lo, packed dwordx2 stores =====
    int bm, bn;
    decode_bid(blockIdx.x, 6, bm, bn);
    gemm_split_core(Ahi, Alo, K, Bwe_hi + (size_t)bn * K, Bwe_lo + (size_t)bn * K, K,
                    K, bm, tid, sA, sB, acc);
#pragma unroll
    for (int i = 0; i < 4; i++) {
      const int row = bm + wr * 64 + i * 16 + (lane & 15);
      u16* rh = out_we_hi + (size_t)row * 768;
      u16* rl = out_we_lo + (size_t)row * 768;
#pragma unroll
      for (int j = 0; j < 4; j++) {
        const int colb = bn + wc * 64 + j * 16 + ((lane >> 4) << 2);
        const float4 bs = *(const float4*)(b1we + colb);
        float g0 = gelu_exact(acc[i][j][0] + bs.x);
        float g1 = gelu_exact(acc[i][j][1] + bs.y);
        float g2 = gelu_exact(acc[i][j][2] + bs.z);
        float g3 = gelu_exact(acc[i][j][3] + bs.w);
        uint2 hv, lv;
        u16 h0 = f2bf(g0), h1 = f2bf(g1), h2 = f2bf(g2), h3 = f2bf(g3);
        hv.x = (uint32_t)h0 | ((uint32_t)h1 << 16);
        hv.y = (uint32_t)h2 | ((uint32_t)h3 << 16);
        lv.x = pk2(g0 - bf2f(h0), g1 - bf2f(h1));
        lv.y = pk2(g2 - bf2f(h2), g3 - bf2f(h3));
        *(uint2*)(rh + colb) = hv;
        *(uint2*)(rl + colb) = lv;
      }
    }
  } else {
    // ===== cls+ew fc1 (N=1536), gelu -> bf16, packed dwordx2 stores =====
    int bm, bn;
    decode_bid(blockIdx.x - 768, 12, bm, bn);
    gemm_core(Ahi, nullptr, nullptr, 768, BT1 + (size_t)bn * K, nullptr, nullptr,
              1, K, bm, tid, sA, sB, acc);
#pragma unroll
    for (int i = 0; i < 4; i++) {
      const int row = bm + wr * 64 + i * 16 + (lane & 15);
      u16* ro = out_ce + (size_t)row * 1536;
#pragma unroll
      for (int j = 0; j < 4; j++) {
        const int colb = bn + wc * 64 + j * 16 + ((lane >> 4) << 2);
        const float4 bs = *(const float4*)(b1ce + colb);
        uint2 hv;
        hv.x = pk2(gelu_exact(acc[i][j][0] + bs.x), gelu_exact(acc[i][j][1] + bs.y));
        hv.y = pk2(gelu_exact(acc[i][j][2] + bs.z), gelu_exact(acc[i][j][3] + bs.w));
        *(uint2*)(ro + colb) = hv;
      }
    }
  }
}

// fused fc2 block plan:
//   bid [0,256)     -> we packed-split half-K blocks (heavy 1.5u -> first):
//                      half = bid>>7, row-chunk r = bid&127; K-range [half*384, half*384+384)
//                      acc = hi*Whi + lo*Whi + hi*Wlo over that K-half -> f32 partial p{half}
//   bid [256,1024)  -> cls (1u, 12 K-tiles)
//   bid [1024,1152) -> ew  (1u) -> bf16 Lew   (last: backfills the drain)
//   (bid&7 XCD band preserved for all groups -> row-chunk passes share an XCD's L2)
__global__ __launch_bounds__(256, 4) void gemm2_fused(
    const u16* __restrict__ h_cls,                  // [16384][1536]: cls cols 0..767, ew cols 768..1535
    const u16* __restrict__ hwe_hi, const u16* __restrict__ hwe_lo,
    const u16* __restrict__ BT2cls, const u16* __restrict__ BT2ew,
    const u16* __restrict__ BT2we_hi, const u16* __restrict__ BT2we_lo,
    const float* __restrict__ b2cls, const float* __restrict__ b2ew,
    const float* __restrict__ b2we,
    u16* __restrict__ Lcls, u16* __restrict__ LewB,
    float* __restrict__ p0, float* __restrict__ p1) {
  __shared__ u16 sA[128 * 64];
  __shared__ u16 sB[128 * 64];
  const int tid = threadIdx.x;
  const int lane = tid & 63;
  const int wr = (tid >> 6) >> 1, wc = (tid >> 6) & 1;

  f32x4 acc[4][4];
#pragma unroll
  for (int i = 0; i < 4; i++)
#pragma unroll
    for (int j = 0; j < 4; j++) acc[i][j] = f32x4{0.f, 0.f, 0.f, 0.f};

  const int bid = blockIdx.x;
  if (bid < 256) {                         // ---- we fc2: packed-split, half-K, dwordx4 f32 stores
    const int half = bid >> 7;
    const int r = bid & 127;
    const int bm = (((r & 7) << 4) + (r >> 3)) << 7;
    const int k0 = half * 384;
    gemm_split_core(hwe_hi + k0, hwe_lo + k0, 768,
                    BT2we_hi + k0, BT2we_lo + k0, 768,
                    384, bm, tid, sA, sB, acc);
    float* o = half ? p1 : p0;
#pragma unroll
    for (int i = 0; i < 4; i++) {
      const int row = bm + wr * 64 + i * 16 + (lane & 15);
#pragma unroll
      for (int j = 0; j < 4; j++) {
        const int colb = wc * 64 + j * 16 + ((lane >> 4) << 2);
        float4 v;
        if (half) {
          v = make_float4(acc[i][j][0], acc[i][j][1], acc[i][j][2], acc[i][j][3]);
        } else {
          const float4 bs = *(const float4*)(b2we + colb);   // bias counted once (half 0)
          v = make_float4(acc[i][j][0] + bs.x, acc[i][j][1] + bs.y,
                          acc[i][j][2] + bs.z, acc[i][j][3] + bs.w);
        }
        *(float4*)(o + (size_t)row * 128 + colb) = v;
      }
    }
  } else if (bid < 1024) {                 // ---- cls: 6 col-tiles, packed dwordx2 stores
    int bm, bn;
    decode_bid(bid - 256, 6, bm, bn);
    gemm_core(h_cls, nullptr, nullptr, 1536, BT2cls + (size_t)bn * 768, nullptr, nullptr,
              1, 768, bm, tid, sA, sB, acc);
#pragma unroll
    for (int i = 0; i < 4; i++) {
      const int row = bm + wr * 64 + i * 16 + (lane & 15);
      u16* ro = Lcls + (size_t)row * 768;
#pragma unroll
      for (int j = 0; j < 4; j++) {
        const int colb = bn + wc * 64 + j * 16 + ((lane >> 4) << 2);
        const float4 bs = *(const float4*)(b2cls + colb);
        uint2 hv;
        hv.x = pk2(acc[i][j][0] + bs.x, acc[i][j][1] + bs.y);
        hv.y = pk2(acc[i][j][2] + bs.z, acc[i][j][3] + bs.w);
        *(uint2*)(ro + colb) = hv;
      }
    }
  } else {                                 // ---- ew (K=768 from h cols 768..1535) -> bf16
    const int r = bid - 1024;
    const int bm = (((r & 7) << 4) + (r >> 3)) << 7;
    gemm_core(h_cls + 768, nullptr, nullptr, 1536, BT2ew, nullptr, nullptr,
              1, 768, bm, tid, sA, sB, acc);
#pragma unroll
    for (int i = 0; i < 4; i++) {
      const int row = bm + wr * 64 + i * 16 + (lane & 15);
      u16* ro = LewB + (size_t)row * 128;
#pragma unroll
      for (int j = 0; j < 4; j++) {
        const int colb = wc * 64 + j * 16 + ((lane >> 4) << 2);
        const float4 bs = *(const float4*)(b2ew + colb);
        uint2 hv;
        hv.x = pk2(acc[i][j][0] + bs.x, acc[i][j][1] + bs.y);
        hv.y = pk2(acc[i][j][2] + bs.z, acc[i][j][3] + bs.w);
        *(uint2*)(ro + colb) = hv;
      }
    }
  }
}

// ---------------- finalize: rank-select mask (== reference threshold), softmaxes, mixture ----------------
// which_expert = p0 + p1 (deterministic f32 sum of the two K-half partials).
// keep_i  <=>  which_i >= n-th largest  <=>  #{j : w_j > w_i} < n   (ties keep both, same as ref)
__global__ __launch_bounds__(256) void finalize(
    const u16* __restrict__ Lcls,   // bf16 [B][768], expert e at cols e*6..e*6+5
    const float* __restrict__ p0, const float* __restrict__ p1,
    const u16* __restrict__ LewB,   // bf16 [B][128]
    const int* __restrict__ nexp, float* __restrict__ out) {
  const int bid = blockIdx.x;
  const int g = ((bid & 7) << 9) + (bid >> 3);      // XCD band matches gemm2's row mapping
  const int b = (g << 2) + (int)(threadIdx.x >> 6); // 4 rows/block, one wave each
  const int lane = threadIdx.x & 63;
  const float NEG = -3.0e38f;
  const size_t base = (size_t)b * 128;
  const float w0 = (lane < 124) ? (p0[base + lane] + p1[base + lane]) : NEG;
  const float w1 = (lane < 60) ? (p0[base + 64 + lane] + p1[base + 64 + lane]) : NEG;
  int r0 = 0, r1 = 0;
#pragma unroll
  for (int j = 0; j < 64; ++j) {
    float v = __shfl(w0, j, 64);
    r0 += (v > w0); r1 += (v > w1);
  }
#pragma unroll
  for (int j = 0; j < 64; ++j) {
    float v = __shfl(w1, j, 64);
    r0 += (v > w0); r1 += (v > w1);
  }
  int n = nexp[b];
  n = n < 1 ? 1 : (n > 124 ? 124 : n);
  const bool k0 = (lane < 124) && (r0 < n);
  const bool k1 = (lane < 60) && (r1 < n);
  float l0 = k0 ? bf2f(LewB[base + lane]) : NEG;
  float l1 = k1 ? bf2f(LewB[base + 64 + lane]) : NEG;
  float mx = fmaxf(l0, l1);
#pragma unroll
  for (int o = 32; o > 0; o >>= 1) mx = fmaxf(mx, __shfl_xor(mx, o, 64));
  float e0 = k0 ? __expf(l0 - mx) : 0.f;
  float e1 = k1 ? __expf(l1 - mx) : 0.f;
  float S = e0 + e1;
#pragma unroll
  for (int o = 32; o > 0; o >>= 1) S += __shfl_xor(S, o, 64);
  float a0 = 0, a1 = 0, a2 = 0, a3 = 0, a4 = 0, a5 = 0;
#pragma unroll
  for (int h = 0; h < 2; ++h) {
    int e = lane + h * 64;
    float we = h ? e1 : e0;
    if (we > 0.f) {
      const u16* lp = Lcls + (size_t)b * 768 + e * 6;
      float c0 = bf2f(lp[0]), c1 = bf2f(lp[1]), c2 = bf2f(lp[2]);
      float c3 = bf2f(lp[3]), c4 = bf2f(lp[4]), c5 = bf2f(lp[5]);
      float m = fmaxf(fmaxf(fmaxf(c0, c1), fmaxf(c2, c3)), fmaxf(c4, c5));
      float q0 = __expf(c0 - m), q1 = __expf(c1 - m), q2 = __expf(c2 - m);
      float q3 = __expf(c3 - m), q4 = __expf(c4 - m), q5 = __expf(c5 - m);
      float inv = we / (q0 + q1 + q2 + q3 + q4 + q5);
      a0 += q0 * inv; a1 += q1 * inv; a2 += q2 * inv;
      a3 += q3 * inv; a4 += q4 * inv; a5 += q5 * inv;
    }
  }
#pragma unroll
  for (int o = 32; o > 0; o >>= 1) {
    a0 += __shfl_xor(a0, o, 64); a1 += __shfl_xor(a1, o, 64);
    a2 += __shfl_xor(a2, o, 64); a3 += __shfl_xor(a3, o, 64);
    a4 += __shfl_xor(a4, o, 64); a5 += __shfl_xor(a5, o, 64);
  }
  if (lane < 6) {
    float v = (lane == 0) ? a0 : (lane == 1) ? a1 : (lane == 2) ? a2
              : (lane == 3) ? a3 : (lane == 4) ? a4 : a5;
    out[(size_t)b * 6 + lane] = v / S;
  }
}

__global__ void fill_sentinel(float* out, int n, float v) {
  int i = blockIdx.x * 256 + threadIdx.x;
  if (i < n) out[i] = v;
}

extern "C" void kernel_launch(void* const* d_in, const int* in_sizes, int n_in,
                              void* d_out, int out_size, void* d_ws, size_t ws_size,
                              hipStream_t stream) {
  const float* x = (const float*)d_in[0];
  const int* nexp = (const int*)d_in[1];
  const float* cls_w1 = (const float*)d_in[2];
  const float* cls_b1 = (const float*)d_in[3];
  const float* cls_w2 = (const float*)d_in[4];
  const float* cls_b2 = (const float*)d_in[5];
  const float* we_w1 = (const float*)d_in[6];
  const float* we_b1 = (const float*)d_in[7];
  const float* we_w2 = (const float*)d_in[8];
  const float* we_b2 = (const float*)d_in[9];
  const float* ew_w1 = (const float*)d_in[10];
  const float* ew_b1 = (const float*)d_in[11];
  const float* ew_w2 = (const float*)d_in[12];
  const float* ew_b2 = (const float*)d_in[13];
  float* out = (float*)d_out;
  char* ws = (char*)d_ws;

  if (ws_size < WS_NEED) {  // diagnosable failure: absmax ~12345
    fill_sentinel<<<(out_size + 255) / 256, 256, 0, stream>>>(out, out_size, 12345.0f);
    return;
  }

  u16* xhi = (u16*)(ws + OFF_XHI);
  u16* xlo = (u16*)(ws + OFF_XLO);
  u16* Lcls = (u16*)(ws + OFF_LCLS);
  float* pwe0 = (float*)(ws + OFF_LWE_P0);
  float* pwe1 = (float*)(ws + OFF_LWE_P1);
  u16* LewB = (u16*)(ws + OFF_LEWB);
  u16* BT1 = (u16*)(ws + OFF_BT1);
  u16* BTwe_hi = (u16*)(ws + OFF_BTWE_HI);
  u16* BTwe_lo = (u16*)(ws + OFF_BTWE_LO);
  u16* BT2cls = (u16*)(ws + OFF_BT2CLS);
  u16* BT2ew = (u16*)(ws + OFF_BT2EW);
  u16* BT2we_hi = (u16*)(ws + OFF_BT2WE_HI);
  u16* BT2we_lo = (u16*)(ws + OFF_BT2WE_LO);
  float* b1ce = (float*)(ws + OFF_B1CE);
  float* b1we = (float*)(ws + OFF_B1WE);
  float* b2cls = (float*)(ws + OFF_B2CLS);
  float* b2ew = (float*)(ws + OFF_B2EW);
  float* b2we = (float*)(ws + OFF_B2WE);
  u16* h_clsew = (u16*)(ws + OFF_HCLSEW);
  u16* h_we_hi = (u16*)(ws + OFF_HWE_HI);
  u16* h_we_lo = (u16*)(ws + OFF_HWE_LO);

  prep_all<<<13165, 256, 0, stream>>>(x, xhi, xlo,
                                      cls_w1, ew_w1, we_w1, cls_w2, ew_w2, we_w2,
                                      BT1, BTwe_hi, BTwe_lo, BT2cls, BT2ew, BT2we_hi, BT2we_lo,
                                      cls_b1, ew_b1, we_b1, cls_b2, ew_b2, we_b2,
                                      b1ce, b1we, b2cls, b2ew, b2we);
  // fc1 BOTH heads in one dispatch: heavy packed-split we blocks first, cls/ew backfills
  gemm1_fused<<<2304, 256, 0, stream>>>(xhi, xlo, BTwe_hi, BTwe_lo, BT1,
                                        b1we, b1ce, h_we_hi, h_we_lo, h_clsew);
  // fc2: 1152 blocks; we packed-split half-K (1.5u) first, cls (1u), ew (1u) backfills drain
  gemm2_fused<<<1152, 256, 0, stream>>>(h_clsew, h_we_hi, h_we_lo,
                                        BT2cls, BT2ew, BT2we_hi, BT2we_lo,
                                        b2cls, b2ew, b2we,
                                        Lcls, LewB, pwe0, pwe1);
  finalize<<<4096, 256, 0, stream>>>(Lcls, pwe0, pwe1, LewB, nexp, out);
}